// Round 14
// baseline (468.973 us; speedup 1.0000x reference)
//
#include <hip/hip_runtime.h>
#include <cstddef>

typedef __bf16 bf16;
typedef __bf16 bf16x8 __attribute__((ext_vector_type(8)));
typedef float  f32x4  __attribute__((ext_vector_type(4)));
typedef unsigned short u16;
typedef unsigned long long u64;

#define MFMA16x16(a, b, c) __builtin_amdgcn_mfma_f32_16x16x32_bf16((a), (b), (c), 0, 0, 0)

namespace {
constexpr int BB   = 4;     // batch
constexpr int CIN  = 128;   // input channels
constexpr int NPT  = 4096;  // points
constexpr int KNBR = 16;    // neighbors
constexpr int HED  = 128;   // hidden (edge mlp out)
constexpr int COUT = 256;   // output channels
}

// ordered-float transform: monotone uint32 over all finite floats
__device__ __forceinline__ unsigned int ord_f32(float f) {
  unsigned int b = __float_as_uint(f);
  return b ^ (0x80000000u | (unsigned int)((int)b >> 31));
}
__device__ __forceinline__ u64 mk_key(float d, int m) {
  return ((u64)ord_f32(d) << 32) | (unsigned int)m;
}

// branch-free bitonic sort of 16 u64 keys, ascending (final survivor stage)
__device__ __forceinline__ void sort16(u64* k) {
  #pragma unroll
  for (int sz = 2; sz <= 16; sz <<= 1) {
    #pragma unroll
    for (int st = sz >> 1; st > 0; st >>= 1) {
      #pragma unroll
      for (int i = 0; i < 16; ++i) {
        const int j = i ^ st;
        if (j > i) {
          const bool up = ((i & sz) == 0);
          const u64 a = k[i], c = k[j];
          const bool sw = up ? (a > c) : (a < c);
          k[i] = sw ? c : a;
          k[j] = sw ? a : c;
        }
      }
    }
  }
}

// R (sorted asc 16) <- lowest 16 of R ∪ B (B sorted asc), sorted asc (u64)
__device__ __forceinline__ void merge16(u64* R, const u64* B) {
  u64 t[16];
  #pragma unroll
  for (int i = 0; i < 16; ++i) {
    const u64 a = R[i], c = B[15 - i];
    t[i] = (a < c) ? a : c;
  }
  #pragma unroll
  for (int st = 8; st > 0; st >>= 1) {
    #pragma unroll
    for (int i = 0; i < 16; ++i) {
      const int j = i ^ st;
      if (j > i) {
        const u64 a = t[i], c = t[j];
        const bool sw = a > c;
        t[i] = sw ? c : a;
        t[j] = sw ? a : c;
      }
    }
  }
  #pragma unroll
  for (int i = 0; i < 16; ++i) R[i] = t[i];
}

// ---- f32 value-only selection network (validated round 4): CE = v_min_f32 +
// v_max_f32, full-rate, no vcc; lists are HALF the registers of u64/f64 keys
// -> peak live state fits the 128-reg arch file (no AGPR round-trip tax). ----
__device__ __forceinline__ void fsort16(float* k) {
  #pragma unroll
  for (int sz = 2; sz <= 16; sz <<= 1) {
    #pragma unroll
    for (int st = sz >> 1; st > 0; st >>= 1) {
      #pragma unroll
      for (int i = 0; i < 16; ++i) {
        const int j = i ^ st;
        if (j > i) {
          const bool up = ((i & sz) == 0);   // compile-time
          const float a = k[i], c = k[j];
          const float lo = fminf(a, c), hi = fmaxf(a, c);
          k[i] = up ? lo : hi;
          k[j] = up ? hi : lo;
        }
      }
    }
  }
}

__device__ __forceinline__ void fmerge16(float* R, const float* B) {
  float t[16];
  #pragma unroll
  for (int i = 0; i < 16; ++i) t[i] = fminf(R[i], B[15 - i]);
  #pragma unroll
  for (int st = 8; st > 0; st >>= 1) {
    #pragma unroll
    for (int i = 0; i < 16; ++i) {
      const int j = i ^ st;
      if (j > i) {
        const float a = t[i], c = t[j];
        t[i] = fminf(a, c);
        t[j] = fmaxf(a, c);
      }
    }
  }
  #pragma unroll
  for (int i = 0; i < 16; ++i) R[i] = t[i];
}

__device__ __forceinline__ void fshfl_merge16(float* R, int mask) {
  float B[16];
  #pragma unroll
  for (int i = 0; i < 16; ++i) B[i] = __shfl_xor(R[i], mask, 64);
  fmerge16(R, B);
}

// ---------------------------------------------------------------------------
// K0: fused prep. Blocks [0,256): transpose x (B,Cin,N) fp32 -> xt_hi/xt_lo
// (B,N,Cin) bf16 split + sq. Blocks [256,640): weight fp32->bf16 conversion.
// Block 640: zero the SE partial-sum buffer (consumed by k_fuse atomics).
// ---------------------------------------------------------------------------
__global__ __launch_bounds__(256) void k_prepw(const float* __restrict__ x,
                                               bf16* __restrict__ xh,
                                               bf16* __restrict__ xl,
                                               float* __restrict__ sq,
                                               const float* __restrict__ We,
                                               const float* __restrict__ Wf,
                                               const float* __restrict__ Wr,
                                               bf16* __restrict__ Web,
                                               bf16* __restrict__ Wfb,
                                               bf16* __restrict__ Wrb,
                                               float* __restrict__ partp) {
  __shared__ __attribute__((aligned(16))) bf16 th[64][136];
  __shared__ __attribute__((aligned(16))) bf16 tl[64][136];
  __shared__ float sqp[4][64];
  const int blk = blockIdx.x;
  const int tid = threadIdx.x;
  if (blk >= 256) {
    if (blk < 640) {
      const int i = (blk - 256) * 256 + tid;   // [0, 3*32768)
      const int a = i >> 15;
      const int j = i & 32767;
      const float* src = (a == 0) ? We : (a == 1) ? Wf : Wr;
      bf16*        dst = (a == 0) ? Web : (a == 1) ? Wfb : Wrb;
      dst[j] = (bf16)src[j];
    } else {
      for (int i = tid; i < 64 * COUT; i += 256) partp[i] = 0.f;
    }
    return;
  }
  const int b   = blk >> 6;
  const int n0  = (blk & 63) << 6;
  const int nl  = tid & 63;
  const int cg  = tid >> 6;
  const float* xb = x + (size_t)b * CIN * NPT;
  float acc = 0.f;
  #pragma unroll
  for (int rep = 0; rep < 32; ++rep) {
    const int c = rep * 4 + cg;
    const float v = xb[(size_t)c * NPT + n0 + nl];
    const bf16 h = (bf16)v;
    const bf16 l = (bf16)(v - (float)h);
    acc += v * v;
    th[nl][c] = h;
    tl[nl][c] = l;
  }
  sqp[cg][nl] = acc;
  __syncthreads();
  bf16* xho = xh + ((size_t)b * NPT + n0) * CIN;
  bf16* xlo = xl + ((size_t)b * NPT + n0) * CIN;
  #pragma unroll
  for (int rep = 0; rep < 32; ++rep) {
    const int e = rep * 256 + tid;
    const int r = e >> 7;
    const int c = e & 127;
    xho[(size_t)r * CIN + c] = th[r][c];
    xlo[(size_t)r * CIN + c] = tl[r][c];
  }
  if (tid < 64) {
    sq[b * NPT + n0 + tid] = sqp[0][tid] + sqp[1][tid] + sqp[2][tid] + sqp[3][tid];
  }
}

// ---------------------------------------------------------------------------
// K1: KNN v14 = round-4 two-pass value/recovery scheme + round-11 XCD swizzle
// + round-13 setprio.
// Round 4 halved selection-VALU busy (101->53 µs) but lost to L2 thrash on
// pass-2 re-reads (FETCH 68 MB, pre-swizzle). The swizzle makes each XCD's
// candidate set L2-resident (round 11: FETCH -> compulsory), so pass-2
// re-reads are L2 hits. Bonus: f32 value lists are HALF the registers of
// u64/f64 key lists -> no AGPR split, full-rate CEs.
// Pass 1: per-lane top-16 f32 DISTANCE VALUES (2-inst CEs), cross-quad shfl
//   merges, LDS tree -> exact per-query 16th-smallest value = threshold.
// Pass 2: re-scan (bitwise-identical d: same MFMA chain + add/fmaf sequence),
//   collect survivors d<=thr via LDS atomics (expected 16/query, cap 32 —
//   validated round 4). Final: u64 (ord(d),idx) sort of survivors -> exact
//   lax.top_k lexicographic tie semantics.
// Revert rule: knn > 145 µs or FETCH >> 12 MB -> restore round-13 k_knn.
// ---------------------------------------------------------------------------
__global__ __launch_bounds__(256, 2) void k_knn(const bf16* __restrict__ xh,
                                                const bf16* __restrict__ xl,
                                                const float* __restrict__ sq,
                                                int* __restrict__ knn_idx) {
  __shared__ float Lf[32][66];          // 32 q x 4 runs x 16 values (+2 pad)
  __shared__ float Thr[32];
  __shared__ unsigned int cnt[32];
  __shared__ u64 buf[32][32];           // survivor keys per query
  const int tid  = threadIdx.x;
  const int w    = tid >> 6;
  const int lane = tid & 63;
  const int col  = lane & 15;
  const int quad = lane >> 4;
  const int bid  = blockIdx.x;
  const int swz  = ((bid & 7) << 6) | (bid >> 3);   // XCD-contiguous remap
  const int b    = swz >> 7;          // 128 blocks per batch
  const int q0   = (swz & 127) << 5;  // 32 queries per block
  const bf16*  xhb = xh + (size_t)b * NPT * CIN;
  const bf16*  xlb = xl + (size_t)b * NPT * CIN;
  const float* sqb = sq + b * NPT;

  // query fragments (B operand), 2 subtiles of 16 queries
  bf16x8 qh[2][4], ql[2][4];
  float sqn[2];
  #pragma unroll
  for (int t = 0; t < 2; ++t) {
    const bf16* qrh = xhb + (size_t)(q0 + t * 16 + col) * CIN + quad * 8;
    const bf16* qrl = xlb + (size_t)(q0 + t * 16 + col) * CIN + quad * 8;
    #pragma unroll
    for (int ks = 0; ks < 4; ++ks) {
      qh[t][ks] = *(const bf16x8*)(qrh + ks * 32);
      ql[t][ks] = *(const bf16x8*)(qrl + ks * 32);
    }
    sqn[t] = sqb[q0 + t * 16 + col];
  }

  float R0[16], R1[16];
  #pragma unroll
  for (int i = 0; i < 16; ++i) {
    R0[i] = __builtin_inff();
    R1[i] = __builtin_inff();
  }

  const int cbase = w << 10;

  // ------------------------- pass 1: values only --------------------------
  for (int mt = 0; mt < 16; ++mt) {
    const int m0 = cbase + (mt << 6);
    float k0v[16], k1v[16];
    __builtin_amdgcn_s_setprio(1);
    #pragma unroll
    for (int cb = 0; cb < 4; ++cb) {
      const bf16* crh = xhb + (size_t)(m0 + cb * 16 + col) * CIN + quad * 8;
      const bf16* crl = xlb + (size_t)(m0 + cb * 16 + col) * CIN + quad * 8;
      f32x4 a0 = {0.f, 0.f, 0.f, 0.f};
      f32x4 a1 = {0.f, 0.f, 0.f, 0.f};
      #pragma unroll
      for (int ks = 0; ks < 4; ++ks) {
        const bf16x8 ch_ = *(const bf16x8*)(crh + ks * 32);
        const bf16x8 cl_ = *(const bf16x8*)(crl + ks * 32);
        a0 = MFMA16x16(cl_, qh[0][ks], a0);
        a0 = MFMA16x16(ch_, ql[0][ks], a0);
        a0 = MFMA16x16(ch_, qh[0][ks], a0);
        a1 = MFMA16x16(cl_, qh[1][ks], a1);
        a1 = MFMA16x16(ch_, ql[1][ks], a1);
        a1 = MFMA16x16(ch_, qh[1][ks], a1);
      }
      const f32x4 sqm = *(const f32x4*)(sqb + m0 + cb * 16 + quad * 4);
      #pragma unroll
      for (int r = 0; r < 4; ++r) {
        const float s0 = sqn[0] + sqm[r];
        const float s1 = sqn[1] + sqm[r];
        k0v[cb * 4 + r] = fmaf(-2.0f, a0[r], s0);
        k1v[cb * 4 + r] = fmaf(-2.0f, a1[r], s1);
      }
    }
    __builtin_amdgcn_s_setprio(0);
    fsort16(k0v); fmerge16(R0, k0v);
    fsort16(k1v); fmerge16(R1, k1v);
  }

  // cross-quad merges -> all 4 quad-lanes hold the wave's best-16 values
  fshfl_merge16(R0, 16);
  fshfl_merge16(R0, 32);
  fshfl_merge16(R1, 16);
  fshfl_merge16(R1, 32);

  if (quad == 0) {
    #pragma unroll
    for (int i = 0; i < 16; ++i) {
      Lf[col][w * 16 + i]      = R0[i];
      Lf[16 | col][w * 16 + i] = R1[i];
    }
  }
  __syncthreads();

  // tree merge across the 4 waves' runs: 4 -> 2 -> 1 (values)
  if (tid < 64) {
    const int q = tid >> 1;
    const int j = tid & 1;
    float A[16], Bv[16];
    #pragma unroll
    for (int i = 0; i < 16; ++i) {
      A[i]  = Lf[q][(2 * j) * 16 + i];
      Bv[i] = Lf[q][(2 * j + 1) * 16 + i];
    }
    fmerge16(A, Bv);
    #pragma unroll
    for (int i = 0; i < 16; ++i) Lf[q][j * 16 + i] = A[i];
  }
  __syncthreads();
  if (tid < 32) {
    float A[16], Bv[16];
    #pragma unroll
    for (int i = 0; i < 16; ++i) {
      A[i]  = Lf[tid][i];
      Bv[i] = Lf[tid][16 + i];
    }
    fmerge16(A, Bv);
    Thr[tid] = A[15];    // exact 16th-smallest distance value for this query
    cnt[tid] = 0;
  }
  __syncthreads();

  const float thr0 = Thr[col];
  const float thr1 = Thr[16 | col];

  // --------------------- pass 2: survivor collection ----------------------
  for (int mt = 0; mt < 16; ++mt) {
    const int m0 = cbase + (mt << 6);
    __builtin_amdgcn_s_setprio(1);
    #pragma unroll
    for (int cb = 0; cb < 4; ++cb) {
      const bf16* crh = xhb + (size_t)(m0 + cb * 16 + col) * CIN + quad * 8;
      const bf16* crl = xlb + (size_t)(m0 + cb * 16 + col) * CIN + quad * 8;
      f32x4 a0 = {0.f, 0.f, 0.f, 0.f};
      f32x4 a1 = {0.f, 0.f, 0.f, 0.f};
      #pragma unroll
      for (int ks = 0; ks < 4; ++ks) {
        const bf16x8 ch_ = *(const bf16x8*)(crh + ks * 32);
        const bf16x8 cl_ = *(const bf16x8*)(crl + ks * 32);
        a0 = MFMA16x16(cl_, qh[0][ks], a0);
        a0 = MFMA16x16(ch_, ql[0][ks], a0);
        a0 = MFMA16x16(ch_, qh[0][ks], a0);
        a1 = MFMA16x16(cl_, qh[1][ks], a1);
        a1 = MFMA16x16(ch_, ql[1][ks], a1);
        a1 = MFMA16x16(ch_, qh[1][ks], a1);
      }
      const f32x4 sqm = *(const f32x4*)(sqb + m0 + cb * 16 + quad * 4);
      #pragma unroll
      for (int r = 0; r < 4; ++r) {
        const int m = m0 + cb * 16 + quad * 4 + r;
        const float s0 = sqn[0] + sqm[r];
        const float s1 = sqn[1] + sqm[r];
        const float d0 = fmaf(-2.0f, a0[r], s0);
        const float d1 = fmaf(-2.0f, a1[r], s1);
        const bool h0 = (d0 <= thr0);
        const bool h1 = (d1 <= thr1);
        if (h0 | h1) {                 // rare: ~16 survivors / query total
          if (h0) {
            const unsigned pos = atomicAdd(&cnt[col], 1u);
            if (pos < 32) buf[col][pos] = mk_key(d0, m);
          }
          if (h1) {
            const unsigned pos = atomicAdd(&cnt[16 | col], 1u);
            if (pos < 32) buf[16 | col][pos] = mk_key(d1, m);
          }
        }
      }
    }
    __builtin_amdgcn_s_setprio(0);
  }
  __syncthreads();

  // ------------- final: exact (d, idx) sort of survivors ------------------
  if (tid < 64) {
    const int q = tid >> 1;
    const int h = tid & 1;
    const unsigned n = cnt[q] < 32u ? cnt[q] : 32u;
    u64 A[16];
    #pragma unroll
    for (int i = 0; i < 16; ++i) {
      const unsigned p = h * 16 + i;
      A[i] = (p < n) ? buf[q][p] : ~0ull;
    }
    sort16(A);
    #pragma unroll
    for (int i = 0; i < 16; ++i) buf[q][h * 16 + i] = A[i];
  }
  __syncthreads();
  if (tid < 32) {
    u64 A[16], Bv[16];
    #pragma unroll
    for (int i = 0; i < 16; ++i) {
      A[i]  = buf[tid][i];
      Bv[i] = buf[tid][16 + i];
    }
    merge16(A, Bv);
    int* op = knn_idx + (size_t)(b * NPT + q0 + tid) * KNBR;
    #pragma unroll
    for (int i = 0; i < 16; ++i) op[i] = (int)(A[i] & 0xFFFFFFFFull);
  }
}

// ---------------------------------------------------------------------------
// K2: edge MLP + attention + aggregate, v12 (kept): LDS-free direct-gather
// fragments. lane(col,quad) gathers edge[col][ks*32+quad*8..+8] directly
// (m = knn_idx[p*16+col]; dv = (bf16)((nh+nl)-(ch+cl)); cv cached for the
// ks>=4 center half). 4 pts/wave, grid 1024, XCD swizzle.
// ---------------------------------------------------------------------------
__global__ __launch_bounds__(256) void k_edge(const bf16* __restrict__ xh,
                                              const bf16* __restrict__ xl,
                                              const int* __restrict__ knn_idx,
                                              const bf16* __restrict__ We,
                                              const float* __restrict__ g1, const float* __restrict__ b1,
                                              const float* __restrict__ m1, const float* __restrict__ v1,
                                              const float* __restrict__ watt,
                                              bf16* __restrict__ agg) {
  __shared__ float s1[HED], t1[HED], wat[HED];
  const int tid  = threadIdx.x;
  const int w    = tid >> 6;
  const int lane = tid & 63;
  const int col  = lane & 15;
  const int quad = lane >> 4;
  if (tid < HED) {
    const float ss = g1[tid] / sqrtf(v1[tid] + 1e-5f);
    s1[tid] = ss;
    t1[tid] = b1[tid] - m1[tid] * ss;
    wat[tid] = watt[tid];
  }
  __syncthreads();
  const int bid = blockIdx.x;
  const int swz = ((bid & 7) << 7) | (bid >> 3);   // XCD-contiguous remap (1024 blocks)
  const int gw  = swz * 4 + w;
  for (int it = 0; it < 4; ++it) {
    const int p = gw * 4 + it;
    const int b = p >> 12;
    const int n = p & 4095;
    const bf16* xhb = xh + (size_t)b * NPT * CIN;
    const bf16* xlb = xl + (size_t)b * NPT * CIN;
    const int m = knn_idx[(size_t)p * KNBR + col];
    const bf16* nrh = xhb + (size_t)m * CIN + quad * 8;
    const bf16* nrl = xlb + (size_t)m * CIN + quad * 8;
    const bf16* crh = xhb + (size_t)n * CIN + quad * 8;
    const bf16* crl = xlb + (size_t)n * CIN + quad * 8;
    const f32x4 zero4 = {0.f, 0.f, 0.f, 0.f};
    f32x4 acc[8];
    #pragma unroll
    for (int hb = 0; hb < 8; ++hb) acc[hb] = zero4;
    bf16x8 cvs[4];
    #pragma unroll
    for (int ks = 0; ks < 4; ++ks) {
      const bf16x8 nh8 = *(const bf16x8*)(nrh + ks * 32);
      const bf16x8 nl8 = *(const bf16x8*)(nrl + ks * 32);
      const bf16x8 ch8 = *(const bf16x8*)(crh + ks * 32);
      const bf16x8 cl8 = *(const bf16x8*)(crl + ks * 32);
      bf16x8 dv, cv;
      #pragma unroll
      for (int e = 0; e < 8; ++e) {
        const float nf = (float)nh8[e] + (float)nl8[e];
        const float cf = (float)ch8[e] + (float)cl8[e];
        dv[e] = (bf16)(nf - cf);
        cv[e] = (bf16)cf;
      }
      cvs[ks] = cv;
      #pragma unroll
      for (int hb = 0; hb < 8; ++hb) {
        const bf16x8 bfv = *(const bf16x8*)(We + (size_t)(hb * 16 + col) * 256 + ks * 32 + quad * 8);
        acc[hb] = MFMA16x16(dv, bfv, acc[hb]);
      }
    }
    #pragma unroll
    for (int ks = 4; ks < 8; ++ks) {
      const bf16x8 af = cvs[ks - 4];
      #pragma unroll
      for (int hb = 0; hb < 8; ++hb) {
        const bf16x8 bfv = *(const bf16x8*)(We + (size_t)(hb * 16 + col) * 256 + ks * 32 + quad * 8);
        acc[hb] = MFMA16x16(af, bfv, acc[hb]);
      }
    }
    float h[8][4];
    float lg[4] = {0.f, 0.f, 0.f, 0.f};
    #pragma unroll
    for (int hb = 0; hb < 8; ++hb) {
      const int hc = hb * 16 + col;
      const float ss = s1[hc], tt = t1[hc], ww = wat[hc];
      #pragma unroll
      for (int r = 0; r < 4; ++r) {
        const float hv = fmaxf(acc[hb][r] * ss + tt, 0.f);
        h[hb][r] = hv;
        lg[r] += hv * ww;
      }
    }
    #pragma unroll
    for (int r = 0; r < 4; ++r) {
      float vv = lg[r];
      vv += __shfl_xor(vv, 1);
      vv += __shfl_xor(vv, 2);
      vv += __shfl_xor(vv, 4);
      vv += __shfl_xor(vv, 8);
      lg[r] = vv;
    }
    float mx = fmaxf(fmaxf(lg[0], lg[1]), fmaxf(lg[2], lg[3]));
    mx = fmaxf(mx, __shfl_xor(mx, 16));
    mx = fmaxf(mx, __shfl_xor(mx, 32));
    float ex[4];
    float sm = 0.f;
    #pragma unroll
    for (int r = 0; r < 4; ++r) { ex[r] = expf(lg[r] - mx); sm += ex[r]; }
    sm += __shfl_xor(sm, 16);
    sm += __shfl_xor(sm, 32);
    const float inv = 1.0f / sm;
    float ag[8];
    #pragma unroll
    for (int hb = 0; hb < 8; ++hb) {
      float a = h[hb][0] * ex[0] + h[hb][1] * ex[1] + h[hb][2] * ex[2] + h[hb][3] * ex[3];
      a += __shfl_xor(a, 16);
      a += __shfl_xor(a, 32);
      ag[hb] = a * inv;
    }
    if (quad == 0) {
      bf16* ao = agg + (size_t)p * HED;
      #pragma unroll
      for (int hb = 0; hb < 8; ++hb) ao[hb * 16 + col] = (bf16)ag[hb];
    }
  }
}

// ---------------------------------------------------------------------------
// K3: fuse GEMM (B*N,128)x(128,256) + bn2 + relu -> outp bf16, WITH fused SE
// partial reduction (round 9, validated): shfl over quads + one atomicAdd per
// (chunk, channel) per wave into partp. ob-split x4: grid 1024 = 4 blocks/CU.
// ---------------------------------------------------------------------------
__global__ __launch_bounds__(256) void k_fuse(const bf16* __restrict__ agg,
                                              const bf16* __restrict__ Wf,
                                              const float* __restrict__ g2, const float* __restrict__ b2,
                                              const float* __restrict__ m2, const float* __restrict__ v2,
                                              bf16* __restrict__ outp,
                                              float* __restrict__ partp) {
  const int tid  = threadIdx.x;
  const int w    = tid >> 6;
  const int lane = tid & 63;
  const int col  = lane & 15;
  const int quad = lane >> 4;
  const int pb   = blockIdx.x >> 2;
  const int obq  = blockIdx.x & 3;
  const int p0   = (pb * 4 + w) * 16;
  const int bc   = p0 >> 8;               // global chunk id [0,64)
  bf16x8 afr[4];
  const bf16* arow = agg + (size_t)(p0 + col) * HED + quad * 8;
  #pragma unroll
  for (int ks = 0; ks < 4; ++ks) afr[ks] = *(const bf16x8*)(arow + ks * 32);
  #pragma unroll
  for (int i = 0; i < 4; ++i) {
    const int ob = obq * 4 + i;
    f32x4 acc = {0.f, 0.f, 0.f, 0.f};
    const bf16* brow = Wf + (size_t)(ob * 16 + col) * HED + quad * 8;
    #pragma unroll
    for (int ks = 0; ks < 4; ++ks)
      acc = MFMA16x16(afr[ks], *(const bf16x8*)(brow + ks * 32), acc);
    const int o = ob * 16 + col;
    const float ss = g2[o] / sqrtf(v2[o] + 1e-5f);
    const float tt = b2[o] - m2[o] * ss;
    float se_s = 0.f;
    #pragma unroll
    for (int r = 0; r < 4; ++r) {
      const float v = fmaxf(acc[r] * ss + tt, 0.f);
      outp[(size_t)(p0 + quad * 4 + r) * COUT + o] = (bf16)v;
      se_s += v;
    }
    // sum over the wave's 16 rows (quads), then one atomic per (bc, o)
    se_s += __shfl_xor(se_s, 16);
    se_s += __shfl_xor(se_s, 32);
    if (quad == 0) atomicAdd(&partp[(size_t)bc * COUT + o], se_s);
  }
}

// ---------------------------------------------------------------------------
// K4: SE stage 2 — mean (from fused partials) -> fc1+relu -> fc2+sigmoid.
// Grid 64 (one block per chunk).
// ---------------------------------------------------------------------------
__global__ __launch_bounds__(256) void k_se2(const float* __restrict__ partp,
                                             const float* __restrict__ f1w, const float* __restrict__ f1b,
                                             const float* __restrict__ f2w, const float* __restrict__ f2b,
                                             float* __restrict__ sse) {
  __shared__ float mean_s[COUT];
  __shared__ float h1[64];
  const int bc  = blockIdx.x;   // b*16 + chunk
  const int tid = threadIdx.x;
  mean_s[tid] = partp[(size_t)bc * COUT + tid] * (1.0f / 256.0f);
  __syncthreads();
  if (tid < 64) {
    float a = f1b[tid];
    for (int c = 0; c < COUT; ++c) a += f1w[tid * COUT + c] * mean_s[c];
    h1[tid] = fmaxf(a, 0.f);
  }
  __syncthreads();
  float a = f2b[tid];
  #pragma unroll
  for (int j = 0; j < 64; ++j) a += f2w[tid * 64 + j] * h1[j];
  sse[(size_t)bc * COUT + tid] = 1.0f / (1.0f + expf(-a));
}

// ---------------------------------------------------------------------------
// K5: residual GEMM + bn3; out = outp*se + res, fp32, transposed (B,Cout,N).
// ob-split x4: grid 1024 = 4 blocks/CU.
// ---------------------------------------------------------------------------
__global__ __launch_bounds__(256) void k_final(const bf16* __restrict__ xh,
                                               const bf16* __restrict__ Wr,
                                               const float* __restrict__ g3, const float* __restrict__ b3,
                                               const float* __restrict__ m3, const float* __restrict__ v3,
                                               const bf16* __restrict__ outp,
                                               const float* __restrict__ sse,
                                               float* __restrict__ out) {
  const int tid  = threadIdx.x;
  const int w    = tid >> 6;
  const int lane = tid & 63;
  const int col  = lane & 15;
  const int quad = lane >> 4;
  const int pb   = blockIdx.x >> 2;
  const int obq  = blockIdx.x & 3;
  const int p0   = (pb * 4 + w) * 16;
  const int b    = p0 >> 12;
  const int n0l  = p0 & 4095;
  bf16x8 afr[4];
  const bf16* arow = xh + (size_t)(p0 + col) * CIN + quad * 8;
  #pragma unroll
  for (int ks = 0; ks < 4; ++ks) afr[ks] = *(const bf16x8*)(arow + ks * 32);
  const float* scb = sse + (size_t)(b * 16 + (n0l >> 8)) * COUT;
  #pragma unroll
  for (int i = 0; i < 4; ++i) {
    const int ob = obq * 4 + i;
    f32x4 acc = {0.f, 0.f, 0.f, 0.f};
    const bf16* brow = Wr + (size_t)(ob * 16 + col) * CIN + quad * 8;
    #pragma unroll
    for (int ks = 0; ks < 4; ++ks)
      acc = MFMA16x16(afr[ks], *(const bf16x8*)(brow + ks * 32), acc);
    const int o = ob * 16 + col;
    const float ss = g3[o] / sqrtf(v3[o] + 1e-5f);
    const float tt = b3[o] - m3[o] * ss;
    const float sc = scb[o];
    f32x4 pk;
    #pragma unroll
    for (int r = 0; r < 4; ++r) {
      const float res = acc[r] * ss + tt;
      pk[r] = (float)outp[(size_t)(p0 + quad * 4 + r) * COUT + o] * sc + res;
    }
    float* op = out + (size_t)(b * COUT + o) * NPT + n0l + quad * 4;
    *(f32x4*)op = pk;
  }
}

// ---------------------------------------------------------------------------
extern "C" void kernel_launch(void* const* d_in, const int* in_sizes, int n_in,
                              void* d_out, int out_size, void* d_ws, size_t ws_size,
                              hipStream_t stream) {
  (void)in_sizes; (void)n_in; (void)out_size; (void)ws_size;
  const float* x    = (const float*)d_in[0];
  const float* We   = (const float*)d_in[1];
  const float* g1   = (const float*)d_in[2];
  const float* b1   = (const float*)d_in[3];
  const float* m1   = (const float*)d_in[4];
  const float* v1   = (const float*)d_in[5];
  const float* watt = (const float*)d_in[6];
  const float* Wf   = (const float*)d_in[7];
  const float* g2   = (const float*)d_in[8];
  const float* b2   = (const float*)d_in[9];
  const float* m2   = (const float*)d_in[10];
  const float* v2   = (const float*)d_in[11];
  const float* f1w  = (const float*)d_in[12];
  const float* f1b  = (const float*)d_in[13];
  const float* f2w  = (const float*)d_in[14];
  const float* f2b  = (const float*)d_in[15];
  const float* Wr   = (const float*)d_in[16];
  const float* g3   = (const float*)d_in[17];
  const float* b3   = (const float*)d_in[18];
  const float* m3   = (const float*)d_in[19];
  const float* v3   = (const float*)d_in[20];

  char* ws = (char*)d_ws;
  size_t off = 0;
  bf16*  xth  = (bf16*)(ws + off);  off += (size_t)BB * NPT * CIN * 2;        // 4 MB
  bf16*  xtl  = (bf16*)(ws + off);  off += (size_t)BB * NPT * CIN * 2;        // 4 MB
  float* sq   = (float*)(ws + off); off += (size_t)BB * NPT * 4;              // 64 KB
  int*   idxp = (int*)(ws + off);   off += (size_t)BB * NPT * KNBR * 4;       // 1 MB
  bf16*  aggp = (bf16*)(ws + off);  off += (size_t)BB * NPT * HED * 2;        // 4 MB
  bf16*  outp = (bf16*)(ws + off);  off += (size_t)BB * NPT * COUT * 2;       // 8 MB
  float* ssep = (float*)(ws + off); off += (size_t)BB * 16 * COUT * 4;        // 64 KB
  float* partp= (float*)(ws + off); off += (size_t)64 * COUT * 4;             // 64 KB
  bf16*  Web  = (bf16*)(ws + off);  off += (size_t)HED * 2 * CIN * 2;         // 64 KB
  bf16*  Wfb  = (bf16*)(ws + off);  off += (size_t)COUT * HED * 2;            // 64 KB
  bf16*  Wrb  = (bf16*)(ws + off);  off += (size_t)COUT * CIN * 2;            // 64 KB

  float* out = (float*)d_out;

  k_prepw<<<641, 256, 0, stream>>>(x, xth, xtl, sq, We, Wf, Wr, Web, Wfb, Wrb, partp);
  k_knn<<<512, 256, 0, stream>>>(xth, xtl, sq, idxp);
  k_edge<<<1024, 256, 0, stream>>>(xth, xtl, idxp, Web, g1, b1, m1, v1, watt, aggp);
  k_fuse<<<1024, 256, 0, stream>>>(aggp, Wfb, g2, b2, m2, v2, outp, partp);
  k_se2<<<64, 256, 0, stream>>>(partp, f1w, f1b, f2w, f2b, ssep);
  k_final<<<1024, 256, 0, stream>>>(xth, Wrb, g3, b3, m3, v3, outp, ssep, out);
}

// Round 15
// 347.014 us; speedup vs baseline: 1.3515x; 1.3515x over previous
//
#include <hip/hip_runtime.h>
#include <cstddef>

typedef __bf16 bf16;
typedef __bf16 bf16x8 __attribute__((ext_vector_type(8)));
typedef float  f32x4  __attribute__((ext_vector_type(4)));
typedef unsigned short u16;
typedef unsigned long long u64;

#define MFMA16x16(a, b, c) __builtin_amdgcn_mfma_f32_16x16x32_bf16((a), (b), (c), 0, 0, 0)

namespace {
constexpr int BB   = 4;     // batch
constexpr int CIN  = 128;   // input channels
constexpr int NPT  = 4096;  // points
constexpr int KNBR = 16;    // neighbors
constexpr int HED  = 128;   // hidden (edge mlp out)
constexpr int COUT = 256;   // output channels
}

// ---------------------------------------------------------------------------
// f64-packed selection keys (validated rounds 6-13).
// key = as_double( (u64)as_uint(d) << 32 | (u64)m << 20 ): for d >= 0 this is
// positive, never NaN/Inf, and VALUE order == lexicographic (d, m). CE =
// v_min_f64 + v_max_f64 (2 insts, no vcc).
// ---------------------------------------------------------------------------
__device__ __forceinline__ double mk_keyd(float d, unsigned mlo /* m<<20 */) {
  const u64 k = ((u64)__float_as_uint(d) << 32) | mlo;
  return __longlong_as_double((long long)k);
}
__device__ __forceinline__ int key_idx(double kd) {
  return (int)((__double_as_longlong(kd) >> 20) & 0xFFF);
}

// branch-free bitonic sort of 16 f64 keys, ascending
__device__ __forceinline__ void sort16d(double* k) {
  #pragma unroll
  for (int sz = 2; sz <= 16; sz <<= 1) {
    #pragma unroll
    for (int st = sz >> 1; st > 0; st >>= 1) {
      #pragma unroll
      for (int i = 0; i < 16; ++i) {
        const int j = i ^ st;
        if (j > i) {
          const bool up = ((i & sz) == 0);   // compile-time
          const double a = k[i], c = k[j];
          const double lo = fmin(a, c), hi = fmax(a, c);
          k[i] = up ? lo : hi;
          k[j] = up ? hi : lo;
        }
      }
    }
  }
}

// R (sorted asc 16) <- lowest 16 of R ∪ B (B sorted asc), sorted asc
__device__ __forceinline__ void merge16d(double* R, const double* B) {
  double t[16];
  #pragma unroll
  for (int i = 0; i < 16; ++i) t[i] = fmin(R[i], B[15 - i]);  // half-cleaner
  #pragma unroll
  for (int st = 8; st > 0; st >>= 1) {
    #pragma unroll
    for (int i = 0; i < 16; ++i) {
      const int j = i ^ st;
      if (j > i) {
        const double a = t[i], c = t[j];
        t[i] = fmin(a, c);
        t[j] = fmax(a, c);
      }
    }
  }
  #pragma unroll
  for (int i = 0; i < 16; ++i) R[i] = t[i];
}

// merge own sorted-16 with partner lane's (lane ^ mask); both lanes keep result
__device__ __forceinline__ void shfl_merge16d(double* R, int mask) {
  double B[16];
  #pragma unroll
  for (int i = 0; i < 16; ++i) B[i] = __shfl_xor(R[i], mask, 64);
  merge16d(R, B);
}

// ---------------------------------------------------------------------------
// K0: fused prep. Blocks [0,256): transpose x (B,Cin,N) fp32 -> xt_hi/xt_lo
// (B,N,Cin) bf16 split + sq. Blocks [256,640): weight fp32->bf16 conversion.
// Block 640: zero the SE partial-sum buffer (consumed by k_fuse atomics).
// ---------------------------------------------------------------------------
__global__ __launch_bounds__(256) void k_prepw(const float* __restrict__ x,
                                               bf16* __restrict__ xh,
                                               bf16* __restrict__ xl,
                                               float* __restrict__ sq,
                                               const float* __restrict__ We,
                                               const float* __restrict__ Wf,
                                               const float* __restrict__ Wr,
                                               bf16* __restrict__ Web,
                                               bf16* __restrict__ Wfb,
                                               bf16* __restrict__ Wrb,
                                               float* __restrict__ partp) {
  __shared__ __attribute__((aligned(16))) bf16 th[64][136];
  __shared__ __attribute__((aligned(16))) bf16 tl[64][136];
  __shared__ float sqp[4][64];
  const int blk = blockIdx.x;
  const int tid = threadIdx.x;
  if (blk >= 256) {
    if (blk < 640) {
      const int i = (blk - 256) * 256 + tid;   // [0, 3*32768)
      const int a = i >> 15;
      const int j = i & 32767;
      const float* src = (a == 0) ? We : (a == 1) ? Wf : Wr;
      bf16*        dst = (a == 0) ? Web : (a == 1) ? Wfb : Wrb;
      dst[j] = (bf16)src[j];
    } else {
      for (int i = tid; i < 64 * COUT; i += 256) partp[i] = 0.f;
    }
    return;
  }
  const int b   = blk >> 6;
  const int n0  = (blk & 63) << 6;
  const int nl  = tid & 63;
  const int cg  = tid >> 6;
  const float* xb = x + (size_t)b * CIN * NPT;
  float acc = 0.f;
  #pragma unroll
  for (int rep = 0; rep < 32; ++rep) {
    const int c = rep * 4 + cg;
    const float v = xb[(size_t)c * NPT + n0 + nl];
    const bf16 h = (bf16)v;
    const bf16 l = (bf16)(v - (float)h);
    acc += v * v;
    th[nl][c] = h;
    tl[nl][c] = l;
  }
  sqp[cg][nl] = acc;
  __syncthreads();
  bf16* xho = xh + ((size_t)b * NPT + n0) * CIN;
  bf16* xlo = xl + ((size_t)b * NPT + n0) * CIN;
  #pragma unroll
  for (int rep = 0; rep < 32; ++rep) {
    const int e = rep * 256 + tid;
    const int r = e >> 7;
    const int c = e & 127;
    xho[(size_t)r * CIN + c] = th[r][c];
    xlo[(size_t)r * CIN + c] = tl[r][c];
  }
  if (tid < 64) {
    sq[b * NPT + n0 + tid] = sqp[0][tid] + sqp[1][tid] + sqp[2][tid] + sqp[3][tid];
  }
}

// ---------------------------------------------------------------------------
// K1: KNN — round-13 version restored verbatim (142.4 µs, best measured).
// Single-pass, 32 queries/block, 2 f64-key lists/lane, launch_bounds(256,2),
// XCD swizzle, setprio(1) around the MFMA/load cluster.
// Closed theories (falsified/captured across rounds 1-14):
//  - occupancy: allocator pins 2 waves/SIMD; any tighter cap splits
//    arch-VGPR/AGPR and spills (r1,2,7); grid growth doesn't help (r5);
//    query-LDS + ks-outer raised pressure (r12).
//  - VALU cost: u64->f64 keys captured (r6, -30%); setprio captured (r13).
//  - L2 locality: XCD swizzle captured (r11, FETCH -> compulsory).
//  - two-pass value/recovery: latency-bound both pre-swizzle (r4) and
//    post-swizzle (r14) — the selection network IS the latency hider.
// ---------------------------------------------------------------------------
__global__ __launch_bounds__(256, 2) void k_knn(const bf16* __restrict__ xh,
                                                const bf16* __restrict__ xl,
                                                const float* __restrict__ sq,
                                                int* __restrict__ knn_idx) {
  __shared__ double Lk[32][66];   // 32 queries x 4 runs x 16 keys (+2 pad)
  const int tid  = threadIdx.x;
  const int w    = tid >> 6;
  const int lane = tid & 63;
  const int col  = lane & 15;
  const int quad = lane >> 4;
  const int bid  = blockIdx.x;
  const int swz  = ((bid & 7) << 6) | (bid >> 3);   // XCD-contiguous remap
  const int b    = swz >> 7;          // 128 blocks per batch
  const int q0   = (swz & 127) << 5;  // 32 queries per block
  const bf16*  xhb = xh + (size_t)b * NPT * CIN;
  const bf16*  xlb = xl + (size_t)b * NPT * CIN;
  const float* sqb = sq + b * NPT;

  // query fragments (B operand), 2 subtiles of 16 queries
  bf16x8 qh[2][4], ql[2][4];
  float sqn[2];
  #pragma unroll
  for (int t = 0; t < 2; ++t) {
    const bf16* qrh = xhb + (size_t)(q0 + t * 16 + col) * CIN + quad * 8;
    const bf16* qrl = xlb + (size_t)(q0 + t * 16 + col) * CIN + quad * 8;
    #pragma unroll
    for (int ks = 0; ks < 4; ++ks) {
      qh[t][ks] = *(const bf16x8*)(qrh + ks * 32);
      ql[t][ks] = *(const bf16x8*)(qrl + ks * 32);
    }
    sqn[t] = sqb[q0 + t * 16 + col];
  }

  const double INF = __builtin_inf();
  double R0[16], R1[16];
  #pragma unroll
  for (int i = 0; i < 16; ++i) { R0[i] = INF; R1[i] = INF; }

  const int cbase = w << 10;
  for (int mt = 0; mt < 16; ++mt) {
    const int m0 = cbase + (mt << 6);
    double k0[16], k1[16];
    __builtin_amdgcn_s_setprio(1);   // favor this wave while in MFMA/load phase
    #pragma unroll
    for (int cb = 0; cb < 4; ++cb) {
      const bf16* crh = xhb + (size_t)(m0 + cb * 16 + col) * CIN + quad * 8;
      const bf16* crl = xlb + (size_t)(m0 + cb * 16 + col) * CIN + quad * 8;
      f32x4 a0 = {0.f, 0.f, 0.f, 0.f};
      f32x4 a1 = {0.f, 0.f, 0.f, 0.f};
      #pragma unroll
      for (int ks = 0; ks < 4; ++ks) {
        const bf16x8 ch_ = *(const bf16x8*)(crh + ks * 32);
        const bf16x8 cl_ = *(const bf16x8*)(crl + ks * 32);
        a0 = MFMA16x16(cl_, qh[0][ks], a0);
        a0 = MFMA16x16(ch_, ql[0][ks], a0);
        a0 = MFMA16x16(ch_, qh[0][ks], a0);
        a1 = MFMA16x16(cl_, qh[1][ks], a1);
        a1 = MFMA16x16(ch_, ql[1][ks], a1);
        a1 = MFMA16x16(ch_, qh[1][ks], a1);
      }
      const f32x4 sqm = *(const f32x4*)(sqb + m0 + cb * 16 + quad * 4);
      const unsigned mlo0 = (unsigned)(m0 + cb * 16 + quad * 4) << 20;
      #pragma unroll
      for (int r = 0; r < 4; ++r) {
        k0[cb * 4 + r] = mk_keyd((sqn[0] + sqm[r]) - 2.0f * a0[r], mlo0 + ((unsigned)r << 20));
        k1[cb * 4 + r] = mk_keyd((sqn[1] + sqm[r]) - 2.0f * a1[r], mlo0 + ((unsigned)r << 20));
      }
    }
    __builtin_amdgcn_s_setprio(0);   // back to normal for the VALU sort phase
    sort16d(k0); merge16d(R0, k0);
    sort16d(k1); merge16d(R1, k1);
  }

  // in-register cross-quad merges: after masks 16 and 32, all 4 quad-lanes of
  // a query column hold the wave's best-16 over its full 1024-candidate range
  shfl_merge16d(R0, 16);
  shfl_merge16d(R0, 32);
  shfl_merge16d(R1, 16);
  shfl_merge16d(R1, 32);

  if (quad == 0) {
    #pragma unroll
    for (int i = 0; i < 16; ++i) {
      Lk[col][w * 16 + i]        = R0[i];
      Lk[16 | col][w * 16 + i]   = R1[i];
    }
  }
  __syncthreads();

  // tree merge across the 4 waves' runs: 4 -> 2 -> 1
  if (tid < 64) {
    const int q = tid >> 1;
    const int j = tid & 1;
    double A[16], Bv[16];
    #pragma unroll
    for (int i = 0; i < 16; ++i) {
      A[i]  = Lk[q][(2 * j) * 16 + i];
      Bv[i] = Lk[q][(2 * j + 1) * 16 + i];
    }
    merge16d(A, Bv);
    #pragma unroll
    for (int i = 0; i < 16; ++i) Lk[q][j * 16 + i] = A[i];
  }
  __syncthreads();
  if (tid < 32) {
    double A[16], Bv[16];
    #pragma unroll
    for (int i = 0; i < 16; ++i) {
      A[i]  = Lk[tid][i];
      Bv[i] = Lk[tid][16 + i];
    }
    merge16d(A, Bv);
    int* op = knn_idx + (size_t)(b * NPT + q0 + tid) * KNBR;
    #pragma unroll
    for (int i = 0; i < 16; ++i) op[i] = key_idx(A[i]);
  }
}

// ---------------------------------------------------------------------------
// K2: edge MLP + attention + aggregate, v12 (kept): LDS-free direct-gather
// fragments. lane(col,quad) gathers edge[col][ks*32+quad*8..+8] directly
// (m = knn_idx[p*16+col]; dv = (bf16)((nh+nl)-(ch+cl)); cv cached for the
// ks>=4 center half). 4 pts/wave, grid 1024, XCD swizzle.
// ---------------------------------------------------------------------------
__global__ __launch_bounds__(256) void k_edge(const bf16* __restrict__ xh,
                                              const bf16* __restrict__ xl,
                                              const int* __restrict__ knn_idx,
                                              const bf16* __restrict__ We,
                                              const float* __restrict__ g1, const float* __restrict__ b1,
                                              const float* __restrict__ m1, const float* __restrict__ v1,
                                              const float* __restrict__ watt,
                                              bf16* __restrict__ agg) {
  __shared__ float s1[HED], t1[HED], wat[HED];
  const int tid  = threadIdx.x;
  const int w    = tid >> 6;
  const int lane = tid & 63;
  const int col  = lane & 15;
  const int quad = lane >> 4;
  if (tid < HED) {
    const float ss = g1[tid] / sqrtf(v1[tid] + 1e-5f);
    s1[tid] = ss;
    t1[tid] = b1[tid] - m1[tid] * ss;
    wat[tid] = watt[tid];
  }
  __syncthreads();
  const int bid = blockIdx.x;
  const int swz = ((bid & 7) << 7) | (bid >> 3);   // XCD-contiguous remap (1024 blocks)
  const int gw  = swz * 4 + w;
  for (int it = 0; it < 4; ++it) {
    const int p = gw * 4 + it;
    const int b = p >> 12;
    const int n = p & 4095;
    const bf16* xhb = xh + (size_t)b * NPT * CIN;
    const bf16* xlb = xl + (size_t)b * NPT * CIN;
    const int m = knn_idx[(size_t)p * KNBR + col];
    const bf16* nrh = xhb + (size_t)m * CIN + quad * 8;
    const bf16* nrl = xlb + (size_t)m * CIN + quad * 8;
    const bf16* crh = xhb + (size_t)n * CIN + quad * 8;
    const bf16* crl = xlb + (size_t)n * CIN + quad * 8;
    const f32x4 zero4 = {0.f, 0.f, 0.f, 0.f};
    f32x4 acc[8];
    #pragma unroll
    for (int hb = 0; hb < 8; ++hb) acc[hb] = zero4;
    bf16x8 cvs[4];
    #pragma unroll
    for (int ks = 0; ks < 4; ++ks) {
      const bf16x8 nh8 = *(const bf16x8*)(nrh + ks * 32);
      const bf16x8 nl8 = *(const bf16x8*)(nrl + ks * 32);
      const bf16x8 ch8 = *(const bf16x8*)(crh + ks * 32);
      const bf16x8 cl8 = *(const bf16x8*)(crl + ks * 32);
      bf16x8 dv, cv;
      #pragma unroll
      for (int e = 0; e < 8; ++e) {
        const float nf = (float)nh8[e] + (float)nl8[e];
        const float cf = (float)ch8[e] + (float)cl8[e];
        dv[e] = (bf16)(nf - cf);
        cv[e] = (bf16)cf;
      }
      cvs[ks] = cv;
      #pragma unroll
      for (int hb = 0; hb < 8; ++hb) {
        const bf16x8 bfv = *(const bf16x8*)(We + (size_t)(hb * 16 + col) * 256 + ks * 32 + quad * 8);
        acc[hb] = MFMA16x16(dv, bfv, acc[hb]);
      }
    }
    #pragma unroll
    for (int ks = 4; ks < 8; ++ks) {
      const bf16x8 af = cvs[ks - 4];
      #pragma unroll
      for (int hb = 0; hb < 8; ++hb) {
        const bf16x8 bfv = *(const bf16x8*)(We + (size_t)(hb * 16 + col) * 256 + ks * 32 + quad * 8);
        acc[hb] = MFMA16x16(af, bfv, acc[hb]);
      }
    }
    float h[8][4];
    float lg[4] = {0.f, 0.f, 0.f, 0.f};
    #pragma unroll
    for (int hb = 0; hb < 8; ++hb) {
      const int hc = hb * 16 + col;
      const float ss = s1[hc], tt = t1[hc], ww = wat[hc];
      #pragma unroll
      for (int r = 0; r < 4; ++r) {
        const float hv = fmaxf(acc[hb][r] * ss + tt, 0.f);
        h[hb][r] = hv;
        lg[r] += hv * ww;
      }
    }
    #pragma unroll
    for (int r = 0; r < 4; ++r) {
      float vv = lg[r];
      vv += __shfl_xor(vv, 1);
      vv += __shfl_xor(vv, 2);
      vv += __shfl_xor(vv, 4);
      vv += __shfl_xor(vv, 8);
      lg[r] = vv;
    }
    float mx = fmaxf(fmaxf(lg[0], lg[1]), fmaxf(lg[2], lg[3]));
    mx = fmaxf(mx, __shfl_xor(mx, 16));
    mx = fmaxf(mx, __shfl_xor(mx, 32));
    float ex[4];
    float sm = 0.f;
    #pragma unroll
    for (int r = 0; r < 4; ++r) { ex[r] = expf(lg[r] - mx); sm += ex[r]; }
    sm += __shfl_xor(sm, 16);
    sm += __shfl_xor(sm, 32);
    const float inv = 1.0f / sm;
    float ag[8];
    #pragma unroll
    for (int hb = 0; hb < 8; ++hb) {
      float a = h[hb][0] * ex[0] + h[hb][1] * ex[1] + h[hb][2] * ex[2] + h[hb][3] * ex[3];
      a += __shfl_xor(a, 16);
      a += __shfl_xor(a, 32);
      ag[hb] = a * inv;
    }
    if (quad == 0) {
      bf16* ao = agg + (size_t)p * HED;
      #pragma unroll
      for (int hb = 0; hb < 8; ++hb) ao[hb * 16 + col] = (bf16)ag[hb];
    }
  }
}

// ---------------------------------------------------------------------------
// K3: fuse GEMM (B*N,128)x(128,256) + bn2 + relu -> outp bf16, WITH fused SE
// partial reduction (round 9, validated): shfl over quads + one atomicAdd per
// (chunk, channel) per wave into partp. ob-split x4: grid 1024 = 4 blocks/CU.
// ---------------------------------------------------------------------------
__global__ __launch_bounds__(256) void k_fuse(const bf16* __restrict__ agg,
                                              const bf16* __restrict__ Wf,
                                              const float* __restrict__ g2, const float* __restrict__ b2,
                                              const float* __restrict__ m2, const float* __restrict__ v2,
                                              bf16* __restrict__ outp,
                                              float* __restrict__ partp) {
  const int tid  = threadIdx.x;
  const int w    = tid >> 6;
  const int lane = tid & 63;
  const int col  = lane & 15;
  const int quad = lane >> 4;
  const int pb   = blockIdx.x >> 2;
  const int obq  = blockIdx.x & 3;
  const int p0   = (pb * 4 + w) * 16;
  const int bc   = p0 >> 8;               // global chunk id [0,64)
  bf16x8 afr[4];
  const bf16* arow = agg + (size_t)(p0 + col) * HED + quad * 8;
  #pragma unroll
  for (int ks = 0; ks < 4; ++ks) afr[ks] = *(const bf16x8*)(arow + ks * 32);
  #pragma unroll
  for (int i = 0; i < 4; ++i) {
    const int ob = obq * 4 + i;
    f32x4 acc = {0.f, 0.f, 0.f, 0.f};
    const bf16* brow = Wf + (size_t)(ob * 16 + col) * HED + quad * 8;
    #pragma unroll
    for (int ks = 0; ks < 4; ++ks)
      acc = MFMA16x16(afr[ks], *(const bf16x8*)(brow + ks * 32), acc);
    const int o = ob * 16 + col;
    const float ss = g2[o] / sqrtf(v2[o] + 1e-5f);
    const float tt = b2[o] - m2[o] * ss;
    float se_s = 0.f;
    #pragma unroll
    for (int r = 0; r < 4; ++r) {
      const float v = fmaxf(acc[r] * ss + tt, 0.f);
      outp[(size_t)(p0 + quad * 4 + r) * COUT + o] = (bf16)v;
      se_s += v;
    }
    // sum over the wave's 16 rows (quads), then one atomic per (bc, o)
    se_s += __shfl_xor(se_s, 16);
    se_s += __shfl_xor(se_s, 32);
    if (quad == 0) atomicAdd(&partp[(size_t)bc * COUT + o], se_s);
  }
}

// ---------------------------------------------------------------------------
// K4: SE stage 2 — mean (from fused partials) -> fc1+relu -> fc2+sigmoid.
// Grid 64 (one block per chunk).
// ---------------------------------------------------------------------------
__global__ __launch_bounds__(256) void k_se2(const float* __restrict__ partp,
                                             const float* __restrict__ f1w, const float* __restrict__ f1b,
                                             const float* __restrict__ f2w, const float* __restrict__ f2b,
                                             float* __restrict__ sse) {
  __shared__ float mean_s[COUT];
  __shared__ float h1[64];
  const int bc  = blockIdx.x;   // b*16 + chunk
  const int tid = threadIdx.x;
  mean_s[tid] = partp[(size_t)bc * COUT + tid] * (1.0f / 256.0f);
  __syncthreads();
  if (tid < 64) {
    float a = f1b[tid];
    for (int c = 0; c < COUT; ++c) a += f1w[tid * COUT + c] * mean_s[c];
    h1[tid] = fmaxf(a, 0.f);
  }
  __syncthreads();
  float a = f2b[tid];
  #pragma unroll
  for (int j = 0; j < 64; ++j) a += f2w[tid * 64 + j] * h1[j];
  sse[(size_t)bc * COUT + tid] = 1.0f / (1.0f + expf(-a));
}

// ---------------------------------------------------------------------------
// K5: residual GEMM + bn3; out = outp*se + res, fp32, transposed (B,Cout,N).
// ob-split x4: grid 1024 = 4 blocks/CU.
// ---------------------------------------------------------------------------
__global__ __launch_bounds__(256) void k_final(const bf16* __restrict__ xh,
                                               const bf16* __restrict__ Wr,
                                               const float* __restrict__ g3, const float* __restrict__ b3,
                                               const float* __restrict__ m3, const float* __restrict__ v3,
                                               const bf16* __restrict__ outp,
                                               const float* __restrict__ sse,
                                               float* __restrict__ out) {
  const int tid  = threadIdx.x;
  const int w    = tid >> 6;
  const int lane = tid & 63;
  const int col  = lane & 15;
  const int quad = lane >> 4;
  const int pb   = blockIdx.x >> 2;
  const int obq  = blockIdx.x & 3;
  const int p0   = (pb * 4 + w) * 16;
  const int b    = p0 >> 12;
  const int n0l  = p0 & 4095;
  bf16x8 afr[4];
  const bf16* arow = xh + (size_t)(p0 + col) * CIN + quad * 8;
  #pragma unroll
  for (int ks = 0; ks < 4; ++ks) afr[ks] = *(const bf16x8*)(arow + ks * 32);
  const float* scb = sse + (size_t)(b * 16 + (n0l >> 8)) * COUT;
  #pragma unroll
  for (int i = 0; i < 4; ++i) {
    const int ob = obq * 4 + i;
    f32x4 acc = {0.f, 0.f, 0.f, 0.f};
    const bf16* brow = Wr + (size_t)(ob * 16 + col) * CIN + quad * 8;
    #pragma unroll
    for (int ks = 0; ks < 4; ++ks)
      acc = MFMA16x16(afr[ks], *(const bf16x8*)(brow + ks * 32), acc);
    const int o = ob * 16 + col;
    const float ss = g3[o] / sqrtf(v3[o] + 1e-5f);
    const float tt = b3[o] - m3[o] * ss;
    const float sc = scb[o];
    f32x4 pk;
    #pragma unroll
    for (int r = 0; r < 4; ++r) {
      const float res = acc[r] * ss + tt;
      pk[r] = (float)outp[(size_t)(p0 + quad * 4 + r) * COUT + o] * sc + res;
    }
    float* op = out + (size_t)(b * COUT + o) * NPT + n0l + quad * 4;
    *(f32x4*)op = pk;
  }
}

// ---------------------------------------------------------------------------
extern "C" void kernel_launch(void* const* d_in, const int* in_sizes, int n_in,
                              void* d_out, int out_size, void* d_ws, size_t ws_size,
                              hipStream_t stream) {
  (void)in_sizes; (void)n_in; (void)out_size; (void)ws_size;
  const float* x    = (const float*)d_in[0];
  const float* We   = (const float*)d_in[1];
  const float* g1   = (const float*)d_in[2];
  const float* b1   = (const float*)d_in[3];
  const float* m1   = (const float*)d_in[4];
  const float* v1   = (const float*)d_in[5];
  const float* watt = (const float*)d_in[6];
  const float* Wf   = (const float*)d_in[7];
  const float* g2   = (const float*)d_in[8];
  const float* b2   = (const float*)d_in[9];
  const float* m2   = (const float*)d_in[10];
  const float* v2   = (const float*)d_in[11];
  const float* f1w  = (const float*)d_in[12];
  const float* f1b  = (const float*)d_in[13];
  const float* f2w  = (const float*)d_in[14];
  const float* f2b  = (const float*)d_in[15];
  const float* Wr   = (const float*)d_in[16];
  const float* g3   = (const float*)d_in[17];
  const float* b3   = (const float*)d_in[18];
  const float* m3   = (const float*)d_in[19];
  const float* v3   = (const float*)d_in[20];

  char* ws = (char*)d_ws;
  size_t off = 0;
  bf16*  xth  = (bf16*)(ws + off);  off += (size_t)BB * NPT * CIN * 2;        // 4 MB
  bf16*  xtl  = (bf16*)(ws + off);  off += (size_t)BB * NPT * CIN * 2;        // 4 MB
  float* sq   = (float*)(ws + off); off += (size_t)BB * NPT * 4;              // 64 KB
  int*   idxp = (int*)(ws + off);   off += (size_t)BB * NPT * KNBR * 4;       // 1 MB
  bf16*  aggp = (bf16*)(ws + off);  off += (size_t)BB * NPT * HED * 2;        // 4 MB
  bf16*  outp = (bf16*)(ws + off);  off += (size_t)BB * NPT * COUT * 2;       // 8 MB
  float* ssep = (float*)(ws + off); off += (size_t)BB * 16 * COUT * 4;        // 64 KB
  float* partp= (float*)(ws + off); off += (size_t)64 * COUT * 4;             // 64 KB
  bf16*  Web  = (bf16*)(ws + off);  off += (size_t)HED * 2 * CIN * 2;         // 64 KB
  bf16*  Wfb  = (bf16*)(ws + off);  off += (size_t)COUT * HED * 2;            // 64 KB
  bf16*  Wrb  = (bf16*)(ws + off);  off += (size_t)COUT * CIN * 2;            // 64 KB

  float* out = (float*)d_out;

  k_prepw<<<641, 256, 0, stream>>>(x, xth, xtl, sq, We, Wf, Wr, Web, Wfb, Wrb, partp);
  k_knn<<<512, 256, 0, stream>>>(xth, xtl, sq, idxp);
  k_edge<<<1024, 256, 0, stream>>>(xth, xtl, idxp, Web, g1, b1, m1, v1, watt, aggp);
  k_fuse<<<1024, 256, 0, stream>>>(aggp, Wfb, g2, b2, m2, v2, outp, partp);
  k_se2<<<64, 256, 0, stream>>>(partp, f1w, f1b, f2w, f2b, ssep);
  k_final<<<1024, 256, 0, stream>>>(xth, Wrb, g3, b3, m3, v3, outp, ssep, out);
}